// Round 3
// baseline (566.190 us; speedup 1.0000x reference)
//
#include <hip/hip_runtime.h>

#define TOK  10560
#define CIMG 3072
#define KHD  1024

typedef unsigned short ushort_t;
typedef unsigned int u32;
using bf16x8 = __attribute__((ext_vector_type(8))) __bf16;
using f32x4  = __attribute__((ext_vector_type(4))) float;

#define GLD_LDS16(gp, lp) __builtin_amdgcn_global_load_lds( \
    (const __attribute__((address_space(1))) u32*)(gp), \
    (__attribute__((address_space(3))) u32*)(lp), 16, 0, 0)

static __device__ __forceinline__ unsigned short f2bf(float f){
  union { float f; unsigned u; } x; x.f = f;
  unsigned r = x.u + 0x7fffu + ((x.u >> 16) & 1u);
  return (unsigned short)(r >> 16);
}
static __device__ __forceinline__ float bf2f(unsigned short u){
  union { unsigned u; float f; } x; x.u = ((unsigned)u) << 16; return x.f;
}
static __device__ __forceinline__ float wave_sum(float v){
  #pragma unroll
  for (int off = 32; off > 0; off >>= 1) v += __shfl_xor(v, off, 64);
  return v;
}

// ---------------- conditioning MLP: emb rows 72..87 (cond rows 64..79) -------
__global__ void k_pre(const float* __restrict__ cond,
                      const float* __restrict__ w1, const float* __restrict__ b1,
                      const float* __restrict__ w2, const float* __restrict__ b2,
                      float* __restrict__ emb){
  __shared__ float cs[16][16];
  __shared__ float h1[16][512];
  int t = threadIdx.x;
  if (t < 256) cs[t >> 4][t & 15] = cond[(64 + (t >> 4)) * 16 + (t & 15)];
  __syncthreads();
  #pragma unroll
  for (int i = 0; i < 8; ++i){
    int idx = t + i * 1024; int r = idx >> 9, c = idx & 511;
    float s = b1[c];
    #pragma unroll
    for (int j = 0; j < 16; ++j) s += cs[r][j] * w1[j * 512 + c];
    h1[r][c] = s / (1.f + __expf(-s));   // silu
  }
  __syncthreads();
  #pragma unroll
  for (int i = 0; i < 8; ++i){
    int idx = t + i * 1024; int r = idx >> 9, c = idx & 511;
    float e = b2[c];
    for (int j = 0; j < 512; ++j) e += h1[r][j] * w2[j * 512 + c];
    emb[idx] = e;
  }
}

// ---------------- kv = mf @ kv_w, split-K partials (deterministic) ----------
__global__ __launch_bounds__(256) void k_kv(const float* __restrict__ emb,
                                            const float* __restrict__ kvw,
                                            float* __restrict__ part){
  int bl = blockIdx.x;                 // 3 l * 8 ntile * 16 kchunk = 384
  int l = bl / 128, rem = bl % 128, nt = rem / 16, kc = rem % 16;
  int n = nt * 256 + threadIdx.x;
  const float* e = emb + 2048 * l + kc * 256;   // mf[l][r] = emb[2048l + r]
  const float* w = kvw + (size_t)(kc * 256) * 2048 + n;
  float acc = 0.f;
  for (int r = 0; r < 256; ++r) acc += e[r] * w[(size_t)r * 2048];
  part[kc * 6144 + l * 2048 + n] = acc;
}

// ---------------- reduce partials, bias, k-RMSNorm ---------------------------
__global__ void k_knorm(const float* __restrict__ part, const float* __restrict__ kvb,
                        const float* __restrict__ knw, float* __restrict__ kn,
                        float* __restrict__ vv){
  int wid = threadIdx.x >> 6, lane = threadIdx.x & 63;
  for (int i = 0; i < 12; ++i){
    int g = wid * 12 + i;               // 0..47 = (l,h)
    int l = g >> 4, h = g & 15;
    int ik = l * 2048 + h * 64 + lane;
    float kk = kvb[h * 64 + lane];
    float v  = kvb[1024 + h * 64 + lane];
    for (int p = 0; p < 16; ++p){ kk += part[p * 6144 + ik]; v += part[p * 6144 + ik + 1024]; }
    float ss = wave_sum(kk * kk);
    kn[l * 1024 + h * 64 + lane] = kk * rsqrtf(ss * (1.f/64.f) + 1e-6f) * knw[lane];
    vv[l * 1024 + h * 64 + lane] = v;
  }
}

// ---------------- transpose + f32->bf16 weight convert: dst[C][R] ------------
__global__ __launch_bounds__(256) void k_tconv(const float* __restrict__ src,
                                               ushort_t* __restrict__ dst,
                                               int R, int C){
  __shared__ float tile[32][33];
  int nTr = R >> 5;
  int tr = blockIdx.x % nTr, tc = blockIdx.x / nTr;
  int r0 = tr * 32, c0 = tc * 32, t = threadIdx.x;
  #pragma unroll
  for (int i = 0; i < 4; ++i){
    int idx = t + i * 256; int r = idx >> 5, c = idx & 31;
    tile[r][c] = src[(size_t)(r0 + r) * C + c0 + c];
  }
  __syncthreads();
  #pragma unroll
  for (int i = 0; i < 4; ++i){
    int idx = t + i * 256; int rr = idx >> 5, cc = idx & 31;
    dst[(size_t)(c0 + rr) * R + r0 + cc] = f2bf(tile[cc][rr]);
  }
}

// ---------------- x f32 -> bf16 streaming convert ----------------------------
__global__ __launch_bounds__(256) void k_xconv(const float* __restrict__ x,
                                               ushort_t* __restrict__ xb, int n4){
  for (int i = blockIdx.x * 256 + threadIdx.x; i < n4; i += gridDim.x * 256){
    float4 v = ((const float4*)x)[i];
    ushort4 o;
    o.x = f2bf(v.x); o.y = f2bf(v.y); o.z = f2bf(v.z); o.w = f2bf(v.w);
    ((ushort4*)xb)[i] = o;
  }
}

// ---------------- 128x128 bf16 MFMA GEMM, 3-deep pipeline, counted vmcnt -----
// A bf16 [M][K], Bt bf16 [N][K]. global_load_lds staging (linear dest),
// chunk-XOR bank swizzle applied to global source + ds_read slot.
// Steady state: vmcnt(8) -> 2 tiles (8 loads/thread) stay in flight across
// barriers; loads for tile t issued 3 K-steps before use.
// EPI 0: out bf16 = acc + bias.  EPI 1: out f32 = acc + bias + resid.
template<int EPI>
__global__ __launch_bounds__(256) void gemm_lds(
    const ushort_t* __restrict__ A, const ushort_t* __restrict__ Bt,
    int Mdim, int Kdim, int Ndim,
    const float* __restrict__ bias, const float* __restrict__ resid,
    void* __restrict__ outp){
  __shared__ __align__(16) unsigned char lds[49152]; // 3 bufs x (A 8K + B 8K)
  const int tid = threadIdx.x;
  const int lane = tid & 63, wid = tid >> 6;
  const int wr = wid >> 1, wc = wid & 1;
  const int l15 = lane & 15, kg = lane >> 4;
  const int ntiles = Ndim >> 7;

  // XCD-aware swizzle (grids 664 / 1992 are both divisible by 8 -> bijective)
  int bid = blockIdx.x;
  const int cpx = gridDim.x >> 3;
  bid = (bid & 7) * cpx + (bid >> 3);
  const int mt = bid / ntiles, nt = bid % ntiles;
  const int mbase = mt << 7, nbase = nt << 7;

  // staging: per wave 2 A-loads + 2 B-loads; each load = 16 rows x 64B.
  // bank swizzle: LDS slot s of row r holds global K-chunk (s ^ ((r>>1)&3)).
  // gload_lds dest is linear (lane*16), so pre-swizzle the GLOBAL chunk.
  const int srow = wid * 32 + (lane >> 2);
  const int schunk = (lane & 3) ^ ((lane >> 3) & 3);
  int ar0 = mbase + srow;      if (ar0 >= Mdim) ar0 = Mdim - 1;
  int ar1 = mbase + srow + 16; if (ar1 >= Mdim) ar1 = Mdim - 1;
  const ushort_t* gA0 = A  + (size_t)ar0 * Kdim + schunk * 8;
  const ushort_t* gA1 = A  + (size_t)ar1 * Kdim + schunk * 8;
  const ushort_t* gB0 = Bt + (size_t)(nbase + srow) * Kdim + schunk * 8;
  const ushort_t* gB1 = Bt + (size_t)(nbase + srow + 16) * Kdim + schunk * 8;
  unsigned char* ldsA0 = lds + (wid * 32) * 64;
  unsigned char* ldsA1 = lds + (wid * 32 + 16) * 64;
  unsigned char* ldsB0 = lds + 8192 + (wid * 32) * 64;
  unsigned char* ldsB1 = lds + 8192 + (wid * 32 + 16) * 64;

  auto stage = [&](int buf, int ks){
    const int kb = ks << 5;
    const int bo = buf * 16384;
    GLD_LDS16(gA0 + kb, ldsA0 + bo);
    GLD_LDS16(gA1 + kb, ldsA1 + bo);
    GLD_LDS16(gB0 + kb, ldsB0 + bo);
    GLD_LDS16(gB1 + kb, ldsB1 + bo);
  };

  // fragment read offsets (chunk slot = kg ^ ((row>>1)&3); row>>1&3 == l15>>1&3)
  const int xk = (kg ^ ((l15 >> 1) & 3)) * 16;
  const unsigned aoff = (unsigned)((wr * 64 + l15) * 64) + xk;
  const unsigned boff = 8192u + (unsigned)((wc * 64 + l15) * 64) + xk;

  f32x4 acc[4][4];
  #pragma unroll
  for (int m = 0; m < 4; ++m)
    #pragma unroll
    for (int n = 0; n < 4; ++n) acc[m][n] = {0.f, 0.f, 0.f, 0.f};

  const int ksteps = Kdim >> 5;   // >= 32 for both GEMMs

  stage(0, 0); stage(1, 1); stage(2, 2);
  asm volatile("s_waitcnt vmcnt(8)" ::: "memory");   // tile 0 landed
  __builtin_amdgcn_s_barrier();

  for (int ks = 0; ks < ksteps; ++ks){
    const unsigned char* base = lds + (ks % 3) * 16384;
    bf16x8 afr[4], bfr[4];
    #pragma unroll
    for (int m = 0; m < 4; ++m) afr[m] = *(const bf16x8*)(base + aoff + m * 1024);
    #pragma unroll
    for (int n = 0; n < 4; ++n) bfr[n] = *(const bf16x8*)(base + boff + n * 1024);
    __builtin_amdgcn_s_setprio(1);
    #pragma unroll
    for (int m = 0; m < 4; ++m)
      #pragma unroll
      for (int n = 0; n < 4; ++n)
        acc[m][n] = __builtin_amdgcn_mfma_f32_16x16x32_bf16(afr[m], bfr[n], acc[m][n], 0, 0, 0);
    __builtin_amdgcn_s_setprio(0);
    __builtin_amdgcn_sched_barrier(0);      // pin reads+MFMA before barrier
    __builtin_amdgcn_s_barrier();           // all waves done reading buf[ks%3]
    if (ks + 3 < ksteps){
      stage(ks % 3, ks + 3);                // overwrite just-consumed buffer
      asm volatile("s_waitcnt vmcnt(8)" ::: "memory");  // tile ks+1 landed
    } else if (ks + 3 == ksteps){
      asm volatile("s_waitcnt vmcnt(4)" ::: "memory");
    } else {
      asm volatile("s_waitcnt vmcnt(0)" ::: "memory");
    }
    __builtin_amdgcn_s_barrier();           // tile ks+1 visible to all waves
  }

  #pragma unroll
  for (int n = 0; n < 4; ++n){
    int col = nbase + wc * 64 + n * 16 + l15;
    float bb = bias[col];
    #pragma unroll
    for (int m = 0; m < 4; ++m){
      #pragma unroll
      for (int j = 0; j < 4; ++j){
        int row = mbase + wr * 64 + m * 16 + kg * 4 + j;
        if (row < Mdim){
          float v = acc[m][n][j] + bb;
          if (EPI == 0){
            ((ushort_t*)outp)[(size_t)row * Ndim + col] = f2bf(v);
          } else {
            size_t o = (size_t)row * Ndim + col;
            ((float*)outp)[o] = v + resid[o];
          }
        }
      }
    }
  }
}

// ---------------- per-token attention over L=3 keys --------------------------
__global__ __launch_bounds__(256) void k_attn(const ushort_t* __restrict__ Qb,
    const float* __restrict__ kn, const float* __restrict__ vv,
    const float* __restrict__ qnw, ushort_t* __restrict__ Ob){
  int wid = threadIdx.x >> 6, lane = threadIdx.x & 63;
  int m = blockIdx.x * 4 + wid;           // grid 2640 * 4 waves = 10560 exact
  float qw = qnw[lane];
  const ushort_t* qrow = Qb + (size_t)m * 1024;
  ushort_t* orow = Ob + (size_t)m * 1024;
  for (int h = 0; h < 16; ++h){
    int ib = h * 64 + lane;
    float q = bf2f(qrow[ib]);
    float ss = wave_sum(q * q);
    float qn = q * rsqrtf(ss * (1.f/64.f) + 1e-6f) * qw;
    float s0 = wave_sum(qn * kn[ib]) * 0.125f;
    float s1 = wave_sum(qn * kn[1024 + ib]) * 0.125f;
    float s2 = wave_sum(qn * kn[2048 + ib]) * 0.125f;
    float mx = fmaxf(s0, fmaxf(s1, s2));
    float e0 = __expf(s0 - mx), e1 = __expf(s1 - mx), e2 = __expf(s2 - mx);
    float inv = 1.f / (e0 + e1 + e2);
    float o = (e0 * vv[ib] + e1 * vv[1024 + ib] + e2 * vv[2048 + ib]) * inv;
    orow[ib] = f2bf(o);
  }
}

extern "C" void kernel_launch(void* const* d_in, const int* in_sizes, int n_in,
                              void* d_out, int out_size, void* d_ws, size_t ws_size,
                              hipStream_t stream){
  const float* x    = (const float*)d_in[0];
  const float* cond = (const float*)d_in[1];
  const float* mew1 = (const float*)d_in[2];
  const float* meb1 = (const float*)d_in[3];
  const float* mew2 = (const float*)d_in[4];
  const float* meb2 = (const float*)d_in[5];
  const float* qw   = (const float*)d_in[6];
  const float* qb   = (const float*)d_in[7];
  const float* kvw  = (const float*)d_in[8];
  const float* kvb  = (const float*)d_in[9];
  const float* qnw  = (const float*)d_in[10];
  const float* knw  = (const float*)d_in[11];
  const float* ow   = (const float*)d_in[12];
  const float* ob   = (const float*)d_in[13];

  char* ws = (char*)d_ws;
  float*    emb    = (float*)(ws + 0);          // 16x512 f32
  float*    kvpart = (float*)(ws + 32768);      // 16x6144 f32
  float*    kn     = (float*)(ws + 425984);     // 3x1024 f32
  float*    vv     = (float*)(ws + 438272);     // 3x1024 f32
  ushort_t* qwt    = (ushort_t*)(ws + 450560);  // [1024][3072] bf16
  ushort_t* owt    = (ushort_t*)(ws + 6742016); // [3072][1024] bf16
  ushort_t* Qbuf   = (ushort_t*)(ws + 13033472);// [10560][1024] bf16
  ushort_t* Obuf   = (ushort_t*)(ws + 34660352);// [10560][1024] bf16

  // xb (bf16 x) lives in d_out's 130MB region: only needed until the Q-GEMM;
  // the final GEMM fully overwrites d_out afterwards. No extra ws needed.
  ushort_t* xb = (ushort_t*)d_out;

  k_pre<<<1, 1024, 0, stream>>>(cond, mew1, meb1, mew2, meb2, emb);
  k_kv<<<384, 256, 0, stream>>>(emb, kvw, kvpart);
  k_knorm<<<1, 256, 0, stream>>>(kvpart, kvb, knw, kn, vv);
  k_tconv<<<3072, 256, 0, stream>>>(qw, qwt, 3072, 1024);
  k_tconv<<<3072, 256, 0, stream>>>(ow, owt, 1024, 3072);
  k_xconv<<<2048, 256, 0, stream>>>(x, xb, (TOK * CIMG) / 4);
  gemm_lds<0><<<83 * 8, 256, 0, stream>>>(xb, qwt, TOK, CIMG, KHD, qb, nullptr, Qbuf);
  k_attn<<<2640, 256, 0, stream>>>(Qbuf, kn, vv, qnw, Obuf);
  gemm_lds<1><<<83 * 24, 256, 0, stream>>>(Obuf, owt, TOK, KHD, CIMG, ob, x, d_out);
}

// Round 4
// 531.391 us; speedup vs baseline: 1.0655x; 1.0655x over previous
//
#include <hip/hip_runtime.h>

#define TOK  10560
#define CIMG 3072
#define KHD  1024

typedef unsigned short ushort_t;
typedef unsigned int u32;
using bf16x8 = __attribute__((ext_vector_type(8))) __bf16;
using f32x4  = __attribute__((ext_vector_type(4))) float;

#define GLD_LDS16(gp, lp) __builtin_amdgcn_global_load_lds( \
    (const __attribute__((address_space(1))) u32*)(gp), \
    (__attribute__((address_space(3))) u32*)(lp), 16, 0, 0)

static __device__ __forceinline__ unsigned short f2bf(float f){
  union { float f; unsigned u; } x; x.f = f;
  unsigned r = x.u + 0x7fffu + ((x.u >> 16) & 1u);
  return (unsigned short)(r >> 16);
}
static __device__ __forceinline__ float bf2f(unsigned short u){
  union { unsigned u; float f; } x; x.u = ((unsigned)u) << 16; return x.f;
}
static __device__ __forceinline__ float wave_sum(float v){
  #pragma unroll
  for (int off = 32; off > 0; off >>= 1) v += __shfl_xor(v, off, 64);
  return v;
}

// ---------------- conditioning MLP: emb rows 72..87 (cond rows 64..79) -------
__global__ void k_pre(const float* __restrict__ cond,
                      const float* __restrict__ w1, const float* __restrict__ b1,
                      const float* __restrict__ w2, const float* __restrict__ b2,
                      float* __restrict__ emb){
  __shared__ float cs[16][16];
  __shared__ float h1[16][512];
  int t = threadIdx.x;
  if (t < 256) cs[t >> 4][t & 15] = cond[(64 + (t >> 4)) * 16 + (t & 15)];
  __syncthreads();
  #pragma unroll
  for (int i = 0; i < 8; ++i){
    int idx = t + i * 1024; int r = idx >> 9, c = idx & 511;
    float s = b1[c];
    #pragma unroll
    for (int j = 0; j < 16; ++j) s += cs[r][j] * w1[j * 512 + c];
    h1[r][c] = s / (1.f + __expf(-s));   // silu
  }
  __syncthreads();
  #pragma unroll
  for (int i = 0; i < 8; ++i){
    int idx = t + i * 1024; int r = idx >> 9, c = idx & 511;
    float e = b2[c];
    for (int j = 0; j < 512; ++j) e += h1[r][j] * w2[j * 512 + c];
    emb[idx] = e;
  }
}

// ---------------- kv = mf @ kv_w, split-K partials (deterministic) ----------
__global__ __launch_bounds__(256) void k_kv(const float* __restrict__ emb,
                                            const float* __restrict__ kvw,
                                            float* __restrict__ part){
  int bl = blockIdx.x;                 // 3 l * 8 ntile * 16 kchunk = 384
  int l = bl / 128, rem = bl % 128, nt = rem / 16, kc = rem % 16;
  int n = nt * 256 + threadIdx.x;
  const float* e = emb + 2048 * l + kc * 256;   // mf[l][r] = emb[2048l + r]
  const float* w = kvw + (size_t)(kc * 256) * 2048 + n;
  float acc = 0.f;
  for (int r = 0; r < 256; ++r) acc += e[r] * w[(size_t)r * 2048];
  part[kc * 6144 + l * 2048 + n] = acc;
}

// ---------------- reduce partials, bias, k-RMSNorm ---------------------------
__global__ void k_knorm(const float* __restrict__ part, const float* __restrict__ kvb,
                        const float* __restrict__ knw, float* __restrict__ kn,
                        float* __restrict__ vv){
  int wid = threadIdx.x >> 6, lane = threadIdx.x & 63;
  for (int i = 0; i < 12; ++i){
    int g = wid * 12 + i;               // 0..47 = (l,h)
    int l = g >> 4, h = g & 15;
    int ik = l * 2048 + h * 64 + lane;
    float kk = kvb[h * 64 + lane];
    float v  = kvb[1024 + h * 64 + lane];
    for (int p = 0; p < 16; ++p){ kk += part[p * 6144 + ik]; v += part[p * 6144 + ik + 1024]; }
    float ss = wave_sum(kk * kk);
    kn[l * 1024 + h * 64 + lane] = kk * rsqrtf(ss * (1.f/64.f) + 1e-6f) * knw[lane];
    vv[l * 1024 + h * 64 + lane] = v;
  }
}

// ---------------- transpose + f32->bf16 weight convert: dst[C][R] ------------
__global__ __launch_bounds__(256) void k_tconv(const float* __restrict__ src,
                                               ushort_t* __restrict__ dst,
                                               int R, int C){
  __shared__ float tile[32][33];
  int nTr = R >> 5;
  int tr = blockIdx.x % nTr, tc = blockIdx.x / nTr;
  int r0 = tr * 32, c0 = tc * 32, t = threadIdx.x;
  #pragma unroll
  for (int i = 0; i < 4; ++i){
    int idx = t + i * 256; int r = idx >> 5, c = idx & 31;
    tile[r][c] = src[(size_t)(r0 + r) * C + c0 + c];
  }
  __syncthreads();
  #pragma unroll
  for (int i = 0; i < 4; ++i){
    int idx = t + i * 256; int rr = idx >> 5, cc = idx & 31;
    dst[(size_t)(c0 + rr) * R + r0 + cc] = f2bf(tile[cc][rr]);
  }
}

// ---------------- x f32 -> bf16 streaming convert ----------------------------
__global__ __launch_bounds__(256) void k_xconv(const float* __restrict__ x,
                                               ushort_t* __restrict__ xb, int n4){
  for (int i = blockIdx.x * 256 + threadIdx.x; i < n4; i += gridDim.x * 256){
    float4 v = ((const float4*)x)[i];
    ushort4 o;
    o.x = f2bf(v.x); o.y = f2bf(v.y); o.z = f2bf(v.z); o.w = f2bf(v.w);
    ((ushort4*)xb)[i] = o;
  }
}

// ---------------- 256x256 bf16 MFMA GEMM, 8 waves, 4-deep LDS ring -----------
// A bf16 [M][K], Bt bf16 [N][K]. BK=32. LDS ring: 4 bufs x (A 16K + B 16K).
// Linear [row][64B] layout: 64B row stride -> b128 frag reads hit all 32 banks
// uniformly (conflict-free, no swizzle needed).
// Safety: stage(ks+3) targets buf consumed in iter ks-1 (reads done before the
// iter ks-1 end barrier); per-wave vmcnt(8)+barrier makes tile ks+1 visible.
// EPI 0: out bf16 = acc + bias (LDS-coalesced stores).
// EPI 1: out f32 = acc + bias + resid.
template<int EPI>
__global__ __launch_bounds__(512, 2) void gemm256(
    const ushort_t* __restrict__ A, const ushort_t* __restrict__ Bt,
    int Mdim, int Kdim, int Ndim,
    const float* __restrict__ bias, const float* __restrict__ resid,
    void* __restrict__ outp){
  __shared__ __align__(16) unsigned char lds[131072];
  const int tid = threadIdx.x;
  const int lane = tid & 63, wid = tid >> 6;
  const int wm = wid >> 2, wn = wid & 3;     // 2 x 4 waves
  const int l15 = lane & 15, kg = lane >> 4;
  const int ntiles = Ndim >> 8;

  // XCD swizzle (grids 168 / 504 both divisible by 8 -> bijective)
  int bid = blockIdx.x;
  const int cpx = gridDim.x >> 3;
  bid = (bid & 7) * cpx + (bid >> 3);
  const int mt = bid / ntiles, nt = bid % ntiles;
  const int mbase = mt << 8, nbase = nt << 8;

  // staging: per wave 2 A-gloads + 2 B-gloads; each = 16 rows x 64B (1KB)
  const int srow = lane >> 2;            // 0..15
  const int sk   = (lane & 3) * 8;       // k-elem offset
  int arow0 = mbase + wid * 32 + srow;
  int arow1 = arow0 + 16;
  if (arow0 >= Mdim) arow0 = Mdim - 1;
  if (arow1 >= Mdim) arow1 = Mdim - 1;
  const ushort_t* gA0 = A  + (size_t)arow0 * Kdim + sk;
  const ushort_t* gA1 = A  + (size_t)arow1 * Kdim + sk;
  const ushort_t* gB0 = Bt + (size_t)(nbase + wid * 32 + srow) * Kdim + sk;
  const ushort_t* gB1 = gB0 + (size_t)16 * Kdim;
  unsigned char* ldsA0 = lds + (wid * 2 + 0) * 1024;
  unsigned char* ldsA1 = lds + (wid * 2 + 1) * 1024;
  unsigned char* ldsB0 = lds + 16384 + (wid * 2 + 0) * 1024;
  unsigned char* ldsB1 = lds + 16384 + (wid * 2 + 1) * 1024;

  auto stageA = [&](int ks){
    const size_t kb = (size_t)(ks << 5);
    const int bo = (ks & 3) << 15;
    GLD_LDS16(gA0 + kb, ldsA0 + bo);
    GLD_LDS16(gA1 + kb, ldsA1 + bo);
  };
  auto stageB = [&](int ks){
    const size_t kb = (size_t)(ks << 5);
    const int bo = (ks & 3) << 15;
    GLD_LDS16(gB0 + kb, ldsB0 + bo);
    GLD_LDS16(gB1 + kb, ldsB1 + bo);
  };

  // fragment read offsets: afr[mi] at aoff+mi*1024, bfr[ni] at boff+ni*1024
  const unsigned aoff = (unsigned)((wm * 128 + l15) * 64 + kg * 16);
  const unsigned boff = 16384u + (unsigned)((wn * 64 + l15) * 64 + kg * 16);

  f32x4 acc[8][4];
  #pragma unroll
  for (int m = 0; m < 8; ++m)
    #pragma unroll
    for (int n = 0; n < 4; ++n) acc[m][n] = {0.f, 0.f, 0.f, 0.f};

  const int ksteps = Kdim >> 5;   // 96 / 32

  stageA(0); stageB(0); stageA(1); stageB(1); stageA(2); stageB(2);
  asm volatile("s_waitcnt vmcnt(8)" ::: "memory");   // tile 0 landed (per wave)
  __builtin_amdgcn_s_barrier();

  for (int ks = 0; ks < ksteps; ++ks){
    const unsigned char* base = lds + ((ks & 3) << 15);
    const bool dostage = (ks + 3 < ksteps);
    bf16x8 afr[4], bfr[4];
    #pragma unroll
    for (int n = 0; n < 4; ++n) bfr[n] = *(const bf16x8*)(base + boff + n * 1024);
    #pragma unroll
    for (int m = 0; m < 4; ++m) afr[m] = *(const bf16x8*)(base + aoff + m * 1024);
    if (dostage) stageA(ks + 3);
    __builtin_amdgcn_s_setprio(1);
    #pragma unroll
    for (int m = 0; m < 4; ++m)
      #pragma unroll
      for (int n = 0; n < 4; ++n)
        acc[m][n] = __builtin_amdgcn_mfma_f32_16x16x32_bf16(afr[m], bfr[n], acc[m][n], 0, 0, 0);
    __builtin_amdgcn_s_setprio(0);
    #pragma unroll
    for (int m = 0; m < 4; ++m) afr[m] = *(const bf16x8*)(base + aoff + (m + 4) * 1024);
    if (dostage) stageB(ks + 3);
    __builtin_amdgcn_s_setprio(1);
    #pragma unroll
    for (int m = 0; m < 4; ++m)
      #pragma unroll
      for (int n = 0; n < 4; ++n)
        acc[m + 4][n] = __builtin_amdgcn_mfma_f32_16x16x32_bf16(afr[m], bfr[n], acc[m + 4][n], 0, 0, 0);
    __builtin_amdgcn_s_setprio(0);
    if (dostage){
      asm volatile("s_waitcnt vmcnt(8)" ::: "memory");   // tile ks+1 landed
    } else if (ks + 3 == ksteps){
      asm volatile("s_waitcnt vmcnt(4)" ::: "memory");
    } else if (ks + 2 == ksteps){
      asm volatile("s_waitcnt vmcnt(0)" ::: "memory");
    }
    __builtin_amdgcn_s_barrier();
  }

  if (EPI == 1){
    // f32 out + residual, 4B stores (16 consecutive lanes = 64B chunks)
    #pragma unroll
    for (int n = 0; n < 4; ++n){
      int col = nbase + wn * 64 + n * 16 + l15;
      float bb = bias[col];
      #pragma unroll
      for (int m = 0; m < 8; ++m){
        #pragma unroll
        for (int j = 0; j < 4; ++j){
          int row = mbase + wm * 128 + m * 16 + kg * 4 + j;
          if (row < Mdim){
            size_t o = (size_t)row * Ndim + col;
            ((float*)outp)[o] = acc[m][n][j] + bb + resid[o];
          }
        }
      }
    }
  } else {
    // bf16 out, coalesced via LDS: 2 chunks of 128 rows x 256 cols
    ushort_t* cbuf = (ushort_t*)lds;
    for (int c = 0; c < 2; ++c){
      if (wm == c){
        #pragma unroll
        for (int n = 0; n < 4; ++n){
          int col = nbase + wn * 64 + n * 16 + l15;
          float bb = bias[col];
          #pragma unroll
          for (int m = 0; m < 8; ++m){
            #pragma unroll
            for (int j = 0; j < 4; ++j)
              cbuf[(m * 16 + kg * 4 + j) * 256 + wn * 64 + n * 16 + l15] =
                  f2bf(acc[m][n][j] + bb);
          }
        }
      }
      __syncthreads();
      #pragma unroll
      for (int it = 0; it < 8; ++it){
        int r = it * 16 + (tid >> 5);          // 0..127
        int cb = (tid & 31) * 8;               // col elems 0..248
        int grow = mbase + c * 128 + r;
        if (grow < Mdim)
          *(uint4*)((ushort_t*)outp + (size_t)grow * Ndim + nbase + cb) =
              *(const uint4*)(cbuf + r * 256 + cb);
      }
      __syncthreads();
    }
  }
}

// ---------------- per-token attention over L=3 keys --------------------------
__global__ __launch_bounds__(256) void k_attn(const ushort_t* __restrict__ Qb,
    const float* __restrict__ kn, const float* __restrict__ vv,
    const float* __restrict__ qnw, ushort_t* __restrict__ Ob){
  int wid = threadIdx.x >> 6, lane = threadIdx.x & 63;
  int m = blockIdx.x * 4 + wid;           // grid 2640 * 4 waves = 10560 exact
  float qw = qnw[lane];
  const ushort_t* qrow = Qb + (size_t)m * 1024;
  ushort_t* orow = Ob + (size_t)m * 1024;
  for (int h = 0; h < 16; ++h){
    int ib = h * 64 + lane;
    float q = bf2f(qrow[ib]);
    float ss = wave_sum(q * q);
    float qn = q * rsqrtf(ss * (1.f/64.f) + 1e-6f) * qw;
    float s0 = wave_sum(qn * kn[ib]) * 0.125f;
    float s1 = wave_sum(qn * kn[1024 + ib]) * 0.125f;
    float s2 = wave_sum(qn * kn[2048 + ib]) * 0.125f;
    float mx = fmaxf(s0, fmaxf(s1, s2));
    float e0 = __expf(s0 - mx), e1 = __expf(s1 - mx), e2 = __expf(s2 - mx);
    float inv = 1.f / (e0 + e1 + e2);
    float o = (e0 * vv[ib] + e1 * vv[1024 + ib] + e2 * vv[2048 + ib]) * inv;
    orow[ib] = f2bf(o);
  }
}

extern "C" void kernel_launch(void* const* d_in, const int* in_sizes, int n_in,
                              void* d_out, int out_size, void* d_ws, size_t ws_size,
                              hipStream_t stream){
  const float* x    = (const float*)d_in[0];
  const float* cond = (const float*)d_in[1];
  const float* mew1 = (const float*)d_in[2];
  const float* meb1 = (const float*)d_in[3];
  const float* mew2 = (const float*)d_in[4];
  const float* meb2 = (const float*)d_in[5];
  const float* qw   = (const float*)d_in[6];
  const float* qb   = (const float*)d_in[7];
  const float* kvw  = (const float*)d_in[8];
  const float* kvb  = (const float*)d_in[9];
  const float* qnw  = (const float*)d_in[10];
  const float* knw  = (const float*)d_in[11];
  const float* ow   = (const float*)d_in[12];
  const float* ob   = (const float*)d_in[13];

  char* ws = (char*)d_ws;
  float*    emb    = (float*)(ws + 0);          // 16x512 f32
  float*    kvpart = (float*)(ws + 32768);      // 16x6144 f32
  float*    kn     = (float*)(ws + 425984);     // 3x1024 f32
  float*    vv     = (float*)(ws + 438272);     // 3x1024 f32
  ushort_t* qwt    = (ushort_t*)(ws + 450560);  // [1024][3072] bf16
  ushort_t* owt    = (ushort_t*)(ws + 6742016); // [3072][1024] bf16
  ushort_t* Qbuf   = (ushort_t*)(ws + 13033472);// [10560][1024] bf16
  ushort_t* Obuf   = (ushort_t*)(ws + 34660352);// [10560][1024] bf16

  // xb (bf16 x) lives in d_out's 130MB region: only needed until the Q-GEMM;
  // the final GEMM fully overwrites d_out afterwards. No extra ws needed.
  ushort_t* xb = (ushort_t*)d_out;

  k_pre<<<1, 1024, 0, stream>>>(cond, mew1, meb1, mew2, meb2, emb);
  k_kv<<<384, 256, 0, stream>>>(emb, kvw, kvpart);
  k_knorm<<<1, 256, 0, stream>>>(kvpart, kvb, knw, kn, vv);
  k_tconv<<<3072, 256, 0, stream>>>(qw, qwt, 3072, 1024);
  k_tconv<<<3072, 256, 0, stream>>>(ow, owt, 1024, 3072);
  k_xconv<<<2048, 256, 0, stream>>>(x, xb, (TOK * CIMG) / 4);
  gemm256<0><<<42 * 4, 512, 0, stream>>>(xb, qwt, TOK, CIMG, KHD, qb, nullptr, Qbuf);
  k_attn<<<2640, 256, 0, stream>>>(Qbuf, kn, vv, qnw, Obuf);
  gemm256<1><<<42 * 12, 512, 0, stream>>>(Obuf, owt, TOK, KHD, CIMG, ob, x, d_out);
}